// Round 4
// baseline (390.294 us; speedup 1.0000x reference)
//
#include <hip/hip_runtime.h>

#define NB 512
#define NC 512
#define HD 128
typedef float4 f4;

// ---- 32KB tile staging (8192 floats), 512 thr x 4 f4, 2-deep prefetch ----
#define TGETn(R, p) { const f4* s_ = (const f4*)(p); _Pragma("unroll") \
  for (int i_ = 0; i_ < 4; ++i_) R[i_] = s_[i_*512 + tid]; }
#define TPUTn(R) { _Pragma("unroll") \
  for (int i_ = 0; i_ < 4; ++i_) ((f4*)Wb)[i_*512 + tid] = R[i_]; }
// one pipeline round: commit reg tile->LDS, issue tile t+2's loads, compute
#define RND(R, NP, ...) { __syncthreads(); TPUTn(R); \
  { const float* np_ = (NP); if (np_) { TGETn(R, np_); } } \
  __syncthreads(); __VA_ARGS__; }
// 64-k matmul chunk: A broadcast from LDS array, W from current Wb tile
#define MMB(ACC, AB, KO) { const float* a_ = (AB); _Pragma("unroll 8") \
  for (int k_ = 0; k_ < 64; ++k_) ACC = fmaf(a_[(KO)+k_], Wb[k_*HD + c], ACC); }

// grid-wide barrier: monotonic counter, device-scope; reset via memset per launch
__device__ __forceinline__ void gbar(unsigned* bar, unsigned target) {
  __syncthreads();
  if (threadIdx.x == 0) {
    __threadfence();
    __hip_atomic_fetch_add(bar, 1u, __ATOMIC_RELEASE, __HIP_MEMORY_SCOPE_AGENT);
    while (__hip_atomic_load(bar, __ATOMIC_ACQUIRE, __HIP_MEMORY_SCOPE_AGENT) < target)
      __builtin_amdgcn_s_sleep(2);
  }
  __syncthreads();
  __threadfence();
}

// Fused RS + layer: block owns 4 node rows. Streams `other` endpoint array for
// the relu-sum (R for bird blocks, S for color blocks), keeps the reduction in
// LDS, then chains aggr -> node MLP -> next-layer u/v, all pipelined.
__device__ __forceinline__ void phase_T(
    int tid, int bid, float* Wb, float* sml,
    const float* xin, const float* uin, const float* vin,
    const float* ew2l, const float* eb2l, const float* nw1l, const float* nb1l,
    const float* nw2l, const float* nb2l, const float* ew1n, const float* eb1n,
    float* xout, float* uout, float* vout, f4* pA, f4* pB) {
  const int c = tid & 127, h = c, slot = tid >> 7;
  const bool bird = bid < 128;
  const int r0 = (bid & 127) * 4;     // row within side
  const int nr0 = bid * 4;            // node row
  const float* mine  = bird ? uin : vin;
  const float* other = bird ? vin : uin;
  TGETn(pA, other); TGETn(pB, other + 8192);
  if (tid < 128) ((f4*)sml)[tid] = ((const f4*)(xin + nr0*HD))[tid];   // xa
  const float base = mine[(r0 + slot)*HD + h];
  float racc = 0.f;
#define RSB { _Pragma("unroll 8") for (int j_ = 0; j_ < 64; ++j_) \
    racc += fmaxf(base + Wb[j_*HD + h], 0.f); }
  RND(pA, other + 2*8192, RSB); RND(pB, other + 3*8192, RSB);
  RND(pA, other + 4*8192, RSB); RND(pB, other + 5*8192, RSB);
  RND(pA, other + 6*8192, RSB); RND(pB, other + 7*8192, RSB);
  RND(pA, ew2l,           RSB); RND(pB, ew2l + 8192,    RSB);
#undef RSB
  sml[512 + slot*HD + h] = racc;                       // rs
  float acc = 512.f * eb2l[c];
  RND(pA, nw1l,          MMB(acc, sml + 512 + slot*HD, 0));
  RND(pB, nw1l + 8192,   MMB(acc, sml + 512 + slot*HD, 64));
  sml[1024 + slot*HD + c] = acc;                       // ag
  acc = nb1l[c];
  RND(pA, nw1l + 16384,  MMB(acc, sml + slot*HD, 0));
  RND(pB, nw1l + 24576,  MMB(acc, sml + slot*HD, 64));
  RND(pA, nw2l,          MMB(acc, sml + 1024 + slot*HD, 0));
  RND(pB, nw2l + 8192,   MMB(acc, sml + 1024 + slot*HD, 64));
  sml[1536 + slot*HD + c] = fmaxf(acc, 0.f);           // h1
  acc = nb2l[c];
  const float* e1h = bird ? ew1n : (ew1n + 16384);
  RND(pA, e1h,           MMB(acc, sml + 1536 + slot*HD, 0));
  RND(pB, e1h + 8192,    MMB(acc, sml + 1536 + slot*HD, 64));
  xout[(nr0 + slot)*HD + c] = acc;
  sml[2048 + slot*HD + c] = acc;                       // x'
  float acc2 = bird ? eb1n[c] : 0.f;
  RND(pA, nullptr,       MMB(acc2, sml + 2048 + slot*HD, 0));
  RND(pB, nullptr,       MMB(acc2, sml + 2048 + slot*HD, 64));
  if (bird) uout[(r0 + slot)*HD + c] = acc2;
  else      vout[(r0 + slot)*HD + c] = acc2;
}

__global__ __launch_bounds__(512) void mega(
    const float* __restrict__ probs, const float* __restrict__ npw,
    const float* __restrict__ npb, const float* __restrict__ ew1,
    const float* __restrict__ eb1, const float* __restrict__ ew2,
    const float* __restrict__ eb2, const float* __restrict__ nw1,
    const float* __restrict__ nb1, const float* __restrict__ nw2,
    const float* __restrict__ nb2, const float* __restrict__ cpw,
    const float* __restrict__ cpb, float* __restrict__ out,
    float* x0, float* x1, float* ua, float* va, float* ub, float* vb,
    int* idx, unsigned* bar) {
  __shared__ float Wb[8192];     // 32KB weight/stream tile
  __shared__ float scr[2048];    // 8KB: sort keys / probs rows / comb
  __shared__ float sml[2560];    // 10KB: xa | rs | ag | h1 | x'
  const int tid = threadIdx.x;
  const int bid = blockIdx.x;
  const int c = tid & 127, h = c, slot = tid >> 7;
  f4 pA[4], pB[4];
  const bool bird = bid < 128;

  // ================= phase A: sort + node init + layer-0 u/v =================
  TGETn(pA, bird ? npw : (ew1 + 16384));
  TGETn(pB, bird ? (npw + 8192) : (ew1 + 24576));
  { // bitonic stable-descending argsort of rows 2*bid, 2*bid+1 (lax.top_k order)
    unsigned long long* keys = (unsigned long long*)scr;
    const int rrow = tid >> 8, e = tid & 255;
    const int sr = 2*bid + rrow;
    unsigned long long* kk = keys + rrow*512;
    unsigned bb0 = __float_as_uint(probs[sr*NC + e]);
    unsigned bb1 = __float_as_uint(probs[sr*NC + e + 256]);
    kk[e]       = (((unsigned long long)(~bb0)) << 32) | (unsigned)e;
    kk[e + 256] = (((unsigned long long)(~bb1)) << 32) | (unsigned)(e + 256);
    __syncthreads();
    for (int ks = 1; ks <= 9; ++ks) {
      for (int js = ks - 1; js >= 0; --js) {
        const int j = 1 << js;
        const int i = ((e >> js) << (js + 1)) | (e & (j - 1));
        unsigned long long a = kk[i], b = kk[i | j];
        if ((a > b) == ((i & (1 << ks)) == 0)) { kk[i] = b; kk[i | j] = a; }
        __syncthreads();
      }
    }
    idx[sr*NC + e]       = (int)(kk[e] & 0xFFFFFFFFull);
    idx[sr*NC + e + 256] = (int)(kk[e + 256] & 0xFFFFFFFFull);
    __syncthreads();
  }
  if (bird) {                     // bird rows 4*bid..+3: x0 = probs@npw+b, u
    ((f4*)scr)[tid] = ((const f4*)(probs + (4*bid)*NC))[tid];   // 4x512 probs
    float acc = npb[c];
    RND(pA, npw + 2*8192, MMB(acc, scr + slot*512, 0));
    RND(pB, npw + 3*8192, MMB(acc, scr + slot*512, 64));
    RND(pA, npw + 4*8192, MMB(acc, scr + slot*512, 128));
    RND(pB, npw + 5*8192, MMB(acc, scr + slot*512, 192));
    RND(pA, npw + 6*8192, MMB(acc, scr + slot*512, 256));
    RND(pB, npw + 7*8192, MMB(acc, scr + slot*512, 320));
    RND(pA, ew1,          MMB(acc, scr + slot*512, 384));
    RND(pB, ew1 + 8192,   MMB(acc, scr + slot*512, 448));
    x0[(4*bid + slot)*HD + c] = acc;
    sml[slot*HD + c] = acc;
    float acc2 = eb1[c];
    RND(pA, nullptr, MMB(acc2, sml + slot*HD, 0));
    RND(pB, nullptr, MMB(acc2, sml + slot*HD, 64));
    ua[(4*bid + slot)*HD + c] = acc2;
  } else {                        // color rows: x0 = npw row + b, v
    const int c0 = 4*(bid - 128);
    float val = npw[(c0 + slot)*HD + c] + npb[c];
    x0[(NB + c0 + slot)*HD + c] = val;
    sml[slot*HD + c] = val;
    float acc2 = 0.f;
    RND(pA, nullptr, MMB(acc2, sml + slot*HD, 0));
    RND(pB, nullptr, MMB(acc2, sml + slot*HD, 64));
    va[(c0 + slot)*HD + c] = acc2;
  }
  gbar(bar, 256);

  // ================= T0 (layer 0), T1 (layer 1) =================
  phase_T(tid, bid, Wb, sml, x0, ua, va,
          ew2, eb2, nw1, nb1, nw2, nb2,
          ew1 + 32768, eb1 + 128, x1, ub, vb, pA, pB);
  gbar(bar, 512);
  phase_T(tid, bid, Wb, sml, x1, ub, vb,
          ew2 + 16384, eb2 + 128, nw1 + 32768, nb1 + 128, nw2 + 16384, nb2 + 128,
          ew1 + 65536, eb1 + 256, x0, ua, va, pA, pB);
  gbar(bar, 768);

  // === TAIL: layer 2 (bird only) R + node MLP + gnn + combine + gather ===
  {
    const float* ew2l = ew2 + 32768;  const float* eb2l = eb2 + 256;
    const float* nw1l = nw1 + 65536;  const float* nb1l = nb1 + 256;
    const float* nw2l = nw2 + 32768;  const float* nb2l = nb2 + 256;
    const int r2 = 2*bid;             // 2 bird rows per block
    TGETn(pA, va); TGETn(pB, va + 8192);
    if (tid < 64) ((f4*)sml)[tid] = ((const f4*)(x0 + r2*HD))[tid];   // xa 2x128
    const float pr0 = probs[r2*NC + tid], pr1 = probs[(r2+1)*NC + tid];
    const int jb = 32*(slot >> 1);                 // j-split: 4 slots = 2 rows x 2 halves
    const float base = ua[(r2 + (slot & 1))*HD + h];
    float racc = 0.f;
#define RSB2 { _Pragma("unroll 8") for (int j_ = 0; j_ < 32; ++j_) \
    racc += fmaxf(base + Wb[(jb + j_)*HD + h], 0.f); }
    RND(pA, va + 2*8192, RSB2); RND(pB, va + 3*8192, RSB2);
    RND(pA, va + 4*8192, RSB2); RND(pB, va + 5*8192, RSB2);
    RND(pA, va + 6*8192, RSB2); RND(pB, va + 7*8192, RSB2);
    RND(pA, ew2l,        RSB2); RND(pB, ew2l + 8192, RSB2);
#undef RSB2
    scr[slot*128 + h] = racc;                      // j-half partials
    float acc = (slot < 2) ? 512.f*eb2l[c] : 0.f;
    RND(pA, nw1l, {
      if (tid < 256) sml[512 + slot*HD + h] = scr[slot*128 + h] + scr[(slot+2)*128 + h];
      __syncthreads();
      if (slot < 2) MMB(acc, sml + 512 + slot*HD, 0); });
    RND(pB, nw1l + 8192,  if (slot < 2) MMB(acc, sml + 512 + slot*HD, 64));
    if (slot < 2) { sml[1024 + slot*HD + c] = acc; acc = nb1l[c]; }
    RND(pA, nw1l + 16384, if (slot < 2) MMB(acc, sml + slot*HD, 0));
    RND(pB, nw1l + 24576, if (slot < 2) MMB(acc, sml + slot*HD, 64));
    RND(pA, nw2l,         if (slot < 2) MMB(acc, sml + 1024 + slot*HD, 0));
    RND(pB, nw2l + 8192,  if (slot < 2) MMB(acc, sml + 1024 + slot*HD, 64));
    if (slot < 2) { sml[1536 + slot*HD + c] = fmaxf(acc, 0.f); acc = nb2l[c]; }
    RND(pA, cpw,          if (slot < 2) MMB(acc, sml + 1536 + slot*HD, 0));
    RND(pB, cpw + 8192,   if (slot < 2) MMB(acc, sml + 1536 + slot*HD, 64));
    if (slot < 2) sml[2048 + slot*HD + c] = acc;   // xo 2x128
    float a0 = cpb[tid], a1 = a0;                  // gnn: thread = one column
#define CPB(T) { _Pragma("unroll") for (int k_ = 0; k_ < 16; ++k_) { \
    float w_ = Wb[k_*512 + tid]; \
    a0 = fmaf(sml[2048 + 16*(T) + k_], w_, a0); \
    a1 = fmaf(sml[2176 + 16*(T) + k_], w_, a1); } }
    RND(pA, cpw + 2*8192, CPB(0)); RND(pB, cpw + 3*8192, CPB(1));
    RND(pA, cpw + 4*8192, CPB(2)); RND(pB, cpw + 5*8192, CPB(3));
    RND(pA, cpw + 6*8192, CPB(4)); RND(pB, cpw + 7*8192, CPB(5));
    RND(pA, nullptr,      CPB(6)); RND(pB, nullptr,      CPB(7));
#undef CPB
    scr[tid] = a0*pr0; scr[512 + tid] = a1*pr1;    // combined scores
    __syncthreads();
    const int i0 = idx[r2*NC + tid], i1 = idx[(r2+1)*NC + tid];
    out[r2*NC + tid]     = 1.f - scr[i0];
    out[(r2+1)*NC + tid] = 1.f - scr[512 + i1];
  }
}

extern "C" void kernel_launch(void* const* d_in, const int* in_sizes, int n_in,
                              void* d_out, int out_size, void* d_ws, size_t ws_size,
                              hipStream_t stream) {
  const float* probs = (const float*)d_in[0];
  const float* npw   = (const float*)d_in[1];
  const float* npb   = (const float*)d_in[2];
  const float* ew1   = (const float*)d_in[3];
  const float* eb1   = (const float*)d_in[4];
  const float* ew2   = (const float*)d_in[5];
  const float* eb2   = (const float*)d_in[6];
  const float* nw1   = (const float*)d_in[7];
  const float* nb1   = (const float*)d_in[8];
  const float* nw2   = (const float*)d_in[9];
  const float* nb2   = (const float*)d_in[10];
  const float* cpw   = (const float*)d_in[11];
  const float* cpb   = (const float*)d_in[12];

  unsigned* bar = (unsigned*)d_ws;
  float* base = (float*)d_ws + 1024;       // skip 4KB barrier page
  float* x0 = base;                        // 1024*128
  float* x1 = x0 + 131072;                 // 1024*128
  float* ua = x1 + 131072;                 // 512*128  (even-layer u)
  float* va = ua + 65536;                  // 512*128
  float* ub = va + 65536;                  // odd-layer u
  float* vb = ub + 65536;
  int*  idx = (int*)(vb + 65536);          // 512*512

  hipMemsetAsync(d_ws, 0, 4096, stream);   // reset grid barrier (graph-safe)
  mega<<<256, 512, 0, stream>>>(probs, npw, npb, ew1, eb1, ew2, eb2, nw1, nb1,
                                nw2, nb2, cpw, cpb, (float*)d_out,
                                x0, x1, ua, va, ub, vb, idx, bar);
}

// Round 5
// 152.935 us; speedup vs baseline: 2.5520x; 2.5520x over previous
//
#include <hip/hip_runtime.h>

#define NB 512
#define NC 512
#define HD 128
typedef float2 f2;
typedef float4 f4;

// ---------------------------------------------------------------------------
// Rank-based stable-descending argsort per row (lax.top_k semantics).
// 512 blocks x 512 threads; all compares from LDS with f4 broadcast reads.
// ---------------------------------------------------------------------------
__global__ __launch_bounds__(512) void k_sort(const float* __restrict__ probs,
                                              int* __restrict__ idx) {
  __shared__ float s[NC];
  const int row = blockIdx.x, t = threadIdx.x;
  s[t] = probs[row * NC + t];
  __syncthreads();
  const float myv = s[t];
  int rank = 0;
#pragma unroll 16
  for (int j4 = 0; j4 < 128; ++j4) {
    f4 sv = ((const f4*)s)[j4];
    int j = j4 * 4;
    rank += (sv.x > myv) || (sv.x == myv && (j + 0) < t);
    rank += (sv.y > myv) || (sv.y == myv && (j + 1) < t);
    rank += (sv.z > myv) || (sv.z == myv && (j + 2) < t);
    rank += (sv.w > myv) || (sv.w == myv && (j + 3) < t);
  }
  idx[row * NC + rank] = t;
}

// ---------------------------------------------------------------------------
// k_init: blocks 0-127 bird rows (x0 = probs@npw+b, u0), 128-255 color rows
// (x0 = npw_row+b, v0). 4 rows/block, 256 thr = 64 f2-colgroups x 4 rows.
// W read straight from L2 as float2, 2 accumulators -> deep load ILP.
// ---------------------------------------------------------------------------
__global__ __launch_bounds__(256) void k_init(
    const float* __restrict__ probs, const float* __restrict__ npw,
    const float* __restrict__ npb, const float* __restrict__ ew1,
    const float* __restrict__ eb1, float* __restrict__ x0,
    float* __restrict__ u, float* __restrict__ v) {
  __shared__ float As[4 * NC];    // bird probs rows (16 KB)
  __shared__ float xs[4 * HD];
  const int tid = threadIdx.x, b = blockIdx.x;
  const int cg = tid & 63, r = tid >> 6;
  const int c0 = 2 * cg, c1 = c0 + 1;
  if (b < 128) {                  // ---- bird ----
    const int r0 = b * 4;
    const f4* p4 = (const f4*)(probs + r0 * NC);
#pragma unroll
    for (int i = 0; i < 2; ++i) ((f4*)As)[i * 256 + tid] = p4[i * 256 + tid];
    __syncthreads();
    const f2* W2 = (const f2*)npw;
    float a0 = npb[c0], a1 = npb[c1];
#pragma unroll 8
    for (int k = 0; k < NC; ++k) {
      float a = As[r * NC + k];
      f2 w = W2[k * 64 + cg];
      a0 = fmaf(a, w.x, a0); a1 = fmaf(a, w.y, a1);
    }
    xs[r * HD + c0] = a0; xs[r * HD + c1] = a1;
    *(f2*)&x0[(r0 + r) * HD + c0] = make_float2(a0, a1);
    __syncthreads();
    const f2* E2 = (const f2*)ew1;                 // top half of edge_w1[0]
    float u0 = eb1[c0], u1 = eb1[c1];
#pragma unroll 8
    for (int k = 0; k < HD; ++k) {
      float a = xs[r * HD + k];
      f2 w = E2[k * 64 + cg];
      u0 = fmaf(a, w.x, u0); u1 = fmaf(a, w.y, u1);
    }
    *(f2*)&u[(r0 + r) * HD + c0] = make_float2(u0, u1);
  } else {                        // ---- color ----
    const int cr0 = (b - 128) * 4;
    f2 wv = ((const f2*)npw)[(cr0 + r) * 64 + cg];
    f2 bb = ((const f2*)npb)[cg];
    float x00 = wv.x + bb.x, x01 = wv.y + bb.y;
    xs[r * HD + c0] = x00; xs[r * HD + c1] = x01;
    *(f2*)&x0[(NB + cr0 + r) * HD + c0] = make_float2(x00, x01);
    __syncthreads();
    const f2* E2 = (const f2*)(ew1 + HD * HD);     // bottom half
    float v0 = 0.f, v1 = 0.f;
#pragma unroll 8
    for (int k = 0; k < HD; ++k) {
      float a = xs[r * HD + k];
      f2 w = E2[k * 64 + cg];
      v0 = fmaf(a, w.x, v0); v1 = fmaf(a, w.y, v1);
    }
    *(f2*)&v[(cr0 + r) * HD + c0] = make_float2(v0, v1);
  }
}

// ---------------------------------------------------------------------------
// k_RS: R_i = sum_j relu(u_i+v_j) (blocks 0-127), S_j = sum_i (128-255).
// 4 rows/block; 8 slots = 4 rows x 2 j-halves; f4 loads of `other` from L2.
// ---------------------------------------------------------------------------
__global__ __launch_bounds__(256) void k_RS(const float* __restrict__ u,
                                            const float* __restrict__ v,
                                            float* __restrict__ RS) {
  __shared__ float part[8 * HD];
  const int tid = threadIdx.x, b = blockIdx.x;
  const int cg = tid & 31;        // f4 col group (4 cols)
  const int slot = tid >> 5;      // 0..7
  const int row = slot & 3, jh = slot >> 2;
  const float *mine, *other; int r0, ob;
  if (b < 128) { mine = u; other = v; r0 = b * 4;         ob = r0; }
  else         { mine = v; other = u; r0 = (b - 128) * 4; ob = NB + r0; }
  f4 base = *(const f4*)&mine[(r0 + row) * HD + 4 * cg];
  const f4* O4 = (const f4*)other;
  f4 acc = make_float4(0.f, 0.f, 0.f, 0.f);
#pragma unroll 8
  for (int j = jh * 256; j < jh * 256 + 256; ++j) {
    f4 o = O4[j * 32 + cg];
    acc.x += fmaxf(base.x + o.x, 0.f);
    acc.y += fmaxf(base.y + o.y, 0.f);
    acc.z += fmaxf(base.z + o.z, 0.f);
    acc.w += fmaxf(base.w + o.w, 0.f);
  }
  *(f4*)&part[slot * HD + 4 * cg] = acc;
  __syncthreads();
#pragma unroll
  for (int i = 0; i < 2; ++i) {
    int oi = i * 256 + tid;
    int rr = oi >> 7, cc = oi & 127;
    RS[(ob + rr) * HD + cc] = part[rr * HD + cc] + part[(rr + 4) * HD + cc];
  }
}

// ---------------------------------------------------------------------------
// k_layer: aggr = RS@ew2+512*b2; x' = MLP([x,aggr]); u/v(next) = x'@ew1n.
// 256 blocks x 4 node rows; intermediates in LDS (10 KB); W from L2 as f2.
// ---------------------------------------------------------------------------
__global__ __launch_bounds__(256) void k_layer(
    const float* __restrict__ xin, const float* __restrict__ RSp,
    const float* __restrict__ ew2l, const float* __restrict__ eb2l,
    const float* __restrict__ nw1l, const float* __restrict__ nb1l,
    const float* __restrict__ nw2l, const float* __restrict__ nb2l,
    const float* __restrict__ ew1n, const float* __restrict__ eb1n,
    float* __restrict__ xout, float* __restrict__ u, float* __restrict__ v) {
  __shared__ float xa[4 * HD], rs[4 * HD], ag[4 * HD], h1[4 * HD], xo[4 * HD];
  const int tid = threadIdx.x, b = blockIdx.x;
  const int cg = tid & 63, r = tid >> 6;
  const int c0 = 2 * cg, c1 = c0 + 1;
  const int nr0 = b * 4;
  const bool bird = b < 128;
  ((f2*)xa)[tid] = ((const f2*)(xin + nr0 * HD))[tid];
  ((f2*)rs)[tid] = ((const f2*)(RSp + nr0 * HD))[tid];
  __syncthreads();
  {                               // aggr
    const f2* W2 = (const f2*)ew2l;
    float a0 = 512.f * eb2l[c0], a1 = 512.f * eb2l[c1];
#pragma unroll 8
    for (int k = 0; k < HD; ++k) {
      float a = rs[r * HD + k]; f2 w = W2[k * 64 + cg];
      a0 = fmaf(a, w.x, a0); a1 = fmaf(a, w.y, a1);
    }
    ag[r * HD + c0] = a0; ag[r * HD + c1] = a1;
  }
  __syncthreads();
  {                               // node MLP layer 1 (k = 256 over [x|aggr])
    const f2* W2 = (const f2*)nw1l;
    float a0 = nb1l[c0], a1 = nb1l[c1];
#pragma unroll 8
    for (int k = 0; k < HD; ++k) {
      float a = xa[r * HD + k]; f2 w = W2[k * 64 + cg];
      a0 = fmaf(a, w.x, a0); a1 = fmaf(a, w.y, a1);
    }
#pragma unroll 8
    for (int k = 0; k < HD; ++k) {
      float a = ag[r * HD + k]; f2 w = W2[(HD + k) * 64 + cg];
      a0 = fmaf(a, w.x, a0); a1 = fmaf(a, w.y, a1);
    }
    h1[r * HD + c0] = fmaxf(a0, 0.f); h1[r * HD + c1] = fmaxf(a1, 0.f);
  }
  __syncthreads();
  {                               // node MLP layer 2
    const f2* W2 = (const f2*)nw2l;
    float a0 = nb2l[c0], a1 = nb2l[c1];
#pragma unroll 8
    for (int k = 0; k < HD; ++k) {
      float a = h1[r * HD + k]; f2 w = W2[k * 64 + cg];
      a0 = fmaf(a, w.x, a0); a1 = fmaf(a, w.y, a1);
    }
    xo[r * HD + c0] = a0; xo[r * HD + c1] = a1;
    *(f2*)&xout[(nr0 + r) * HD + c0] = make_float2(a0, a1);
  }
  if (!ew1n) return;              // last layer: no next-layer u/v
  __syncthreads();
  {                               // next-layer u/v
    const f2* W2 = (const f2*)(bird ? ew1n : (ew1n + HD * HD));
    float a0 = bird ? eb1n[c0] : 0.f, a1 = bird ? eb1n[c1] : 0.f;
#pragma unroll 8
    for (int k = 0; k < HD; ++k) {
      float a = xo[r * HD + k]; f2 w = W2[k * 64 + cg];
      a0 = fmaf(a, w.x, a0); a1 = fmaf(a, w.y, a1);
    }
    if (bird) *(f2*)&u[(nr0 + r) * HD + c0]      = make_float2(a0, a1);
    else      *(f2*)&v[(nr0 - NB + r) * HD + c0] = make_float2(a0, a1);
  }
}

// ---------------------------------------------------------------------------
// k_final: gnn = x_bird@cpw+b; combined = gnn*probs; out = 1-comb[idx].
// 128 blocks x 4 bird rows; thread owns one f2 column pair, 8 accumulators.
// ---------------------------------------------------------------------------
__global__ __launch_bounds__(256) void k_final(
    const float* __restrict__ xf, const float* __restrict__ cpw,
    const float* __restrict__ cpb, const float* __restrict__ probs,
    const int* __restrict__ idx, float* __restrict__ out) {
  __shared__ float xb[4 * HD];
  __shared__ float comb[4 * NC];  // 8 KB
  const int tid = threadIdx.x;
  const int r0 = blockIdx.x * 4;
  ((f2*)xb)[tid] = ((const f2*)(xf + r0 * HD))[tid];
  __syncthreads();
  const f2* W2 = (const f2*)cpw;  // [128][256 f2-cols]
  f2 bb = ((const f2*)cpb)[tid];
  float a00 = bb.x, a01 = bb.y, a10 = bb.x, a11 = bb.y;
  float a20 = bb.x, a21 = bb.y, a30 = bb.x, a31 = bb.y;
#pragma unroll 4
  for (int k = 0; k < HD; ++k) {
    f2 w = W2[k * 256 + tid];
    float x0v = xb[k], x1v = xb[HD + k], x2v = xb[2 * HD + k], x3v = xb[3 * HD + k];
    a00 = fmaf(x0v, w.x, a00); a01 = fmaf(x0v, w.y, a01);
    a10 = fmaf(x1v, w.x, a10); a11 = fmaf(x1v, w.y, a11);
    a20 = fmaf(x2v, w.x, a20); a21 = fmaf(x2v, w.y, a21);
    a30 = fmaf(x3v, w.x, a30); a31 = fmaf(x3v, w.y, a31);
  }
  f2 p0 = ((const f2*)(probs + (r0 + 0) * NC))[tid];
  f2 p1 = ((const f2*)(probs + (r0 + 1) * NC))[tid];
  f2 p2 = ((const f2*)(probs + (r0 + 2) * NC))[tid];
  f2 p3 = ((const f2*)(probs + (r0 + 3) * NC))[tid];
  *(f2*)&comb[0 * NC + 2 * tid] = make_float2(a00 * p0.x, a01 * p0.y);
  *(f2*)&comb[1 * NC + 2 * tid] = make_float2(a10 * p1.x, a11 * p1.y);
  *(f2*)&comb[2 * NC + 2 * tid] = make_float2(a20 * p2.x, a21 * p2.y);
  *(f2*)&comb[3 * NC + 2 * tid] = make_float2(a30 * p3.x, a31 * p3.y);
  __syncthreads();
#pragma unroll
  for (int r = 0; r < 4; ++r)
#pragma unroll
    for (int i = 0; i < 2; ++i) {
      int j = i * 256 + tid;
      int cc = idx[(r0 + r) * NC + j];
      out[(r0 + r) * NC + j] = 1.f - comb[r * NC + cc];
    }
}

extern "C" void kernel_launch(void* const* d_in, const int* in_sizes, int n_in,
                              void* d_out, int out_size, void* d_ws, size_t ws_size,
                              hipStream_t stream) {
  const float* probs = (const float*)d_in[0];
  const float* npw   = (const float*)d_in[1];
  const float* npb   = (const float*)d_in[2];
  const float* ew1   = (const float*)d_in[3];
  const float* eb1   = (const float*)d_in[4];
  const float* ew2   = (const float*)d_in[5];
  const float* eb2   = (const float*)d_in[6];
  const float* nw1   = (const float*)d_in[7];
  const float* nb1   = (const float*)d_in[8];
  const float* nw2   = (const float*)d_in[9];
  const float* nb2   = (const float*)d_in[10];
  const float* cpw   = (const float*)d_in[11];
  const float* cpb   = (const float*)d_in[12];
  float* out = (float*)d_out;

  float* x0 = (float*)d_ws;          // 1024*128
  float* x1 = x0 + 1024 * HD;        // 1024*128
  float* ua = x1 + 1024 * HD;        // 512*128
  float* va = ua + NB * HD;
  float* ub = va + NC * HD;
  float* vb = ub + NB * HD;
  float* RS = vb + NC * HD;          // 1024*128
  int*  idx = (int*)(RS + 1024 * HD);

  k_sort <<<512, 512, 0, stream>>>(probs, idx);
  k_init <<<256, 256, 0, stream>>>(probs, npw, npb, ew1, eb1, x0, ua, va);

  // layer 0: x0 -> x1, (ua,va) -> (ub,vb)
  k_RS   <<<256, 256, 0, stream>>>(ua, va, RS);
  k_layer<<<256, 256, 0, stream>>>(x0, RS, ew2, eb2, nw1, nb1, nw2, nb2,
                                   ew1 + 32768, eb1 + HD, x1, ub, vb);
  // layer 1: x1 -> x0, (ub,vb) -> (ua,va)
  k_RS   <<<256, 256, 0, stream>>>(ub, vb, RS);
  k_layer<<<256, 256, 0, stream>>>(x1, RS, ew2 + 16384, eb2 + HD,
                                   nw1 + 32768, nb1 + HD, nw2 + 16384, nb2 + HD,
                                   ew1 + 65536, eb1 + 2 * HD, x0, ua, va);
  // layer 2: x0 -> x1, no next u/v
  k_RS   <<<256, 256, 0, stream>>>(ua, va, RS);
  k_layer<<<256, 256, 0, stream>>>(x0, RS, ew2 + 32768, eb2 + 2 * HD,
                                   nw1 + 65536, nb1 + 2 * HD, nw2 + 32768, nb2 + 2 * HD,
                                   nullptr, nullptr, x1, nullptr, nullptr);
  // epilogue: gnn + combine + gather
  k_final<<<128, 256, 0, stream>>>(x1, cpw, cpb, probs, idx, out);
}

// Round 6
// 137.524 us; speedup vs baseline: 2.8380x; 1.1121x over previous
//
#include <hip/hip_runtime.h>

#define NB 512
#define NC 512
#define HD 128
typedef float2 f2;
typedef float4 f4;

// 8-accumulator k-split matmul step: thread = (cg: f2 output col, slot: k-quarter)
// Each weight load feeds 8 FMAs (4 rows x 2 cols); loads are fully independent.
#define ACC8(SRC, WP, KQ) { const f2* W2_ = (const f2*)(WP); \
  _Pragma("unroll 8") for (int kk_ = 0; kk_ < (KQ); ++kk_) { \
    int k_ = slot * (KQ) + kk_; \
    f2 w_ = W2_[k_ * 64 + cg]; \
    float s0_ = SRC[0][k_], s1_ = SRC[1][k_], s2_ = SRC[2][k_], s3_ = SRC[3][k_]; \
    a0 = fmaf(s0_, w_.x, a0); a1 = fmaf(s0_, w_.y, a1); \
    a2 = fmaf(s1_, w_.x, a2); a3 = fmaf(s1_, w_.y, a3); \
    a4 = fmaf(s2_, w_.x, a4); a5 = fmaf(s2_, w_.y, a5); \
    a6 = fmaf(s3_, w_.x, a6); a7 = fmaf(s3_, w_.y, a7); } }

#define ZACC() { a0=a1=a2=a3=a4=a5=a6=a7=0.f; }
#define WRPART() { *(f2*)&part[slot][0][c0] = make_float2(a0, a1); \
  *(f2*)&part[slot][1][c0] = make_float2(a2, a3); \
  *(f2*)&part[slot][2][c0] = make_float2(a4, a5); \
  *(f2*)&part[slot][3][c0] = make_float2(a6, a7); }
#define PSUM(r_, cc_) (part[0][r_][cc_] + part[1][r_][cc_] + part[2][r_][cc_] + part[3][r_][cc_])

// ---------------------------------------------------------------------------
// Rank-based stable-descending argsort per row (lax.top_k semantics).
// ---------------------------------------------------------------------------
__global__ __launch_bounds__(512) void k_sort(const float* __restrict__ probs,
                                              int* __restrict__ idx) {
  __shared__ float s[NC];
  const int row = blockIdx.x, t = threadIdx.x;
  s[t] = probs[row * NC + t];
  __syncthreads();
  const float myv = s[t];
  int rank = 0;
#pragma unroll 16
  for (int j4 = 0; j4 < 128; ++j4) {
    f4 sv = ((const f4*)s)[j4];
    int j = j4 * 4;
    rank += (sv.x > myv) || (sv.x == myv && (j + 0) < t);
    rank += (sv.y > myv) || (sv.y == myv && (j + 1) < t);
    rank += (sv.z > myv) || (sv.z == myv && (j + 2) < t);
    rank += (sv.w > myv) || (sv.w == myv && (j + 3) < t);
  }
  idx[row * NC + rank] = t;
}

// ---------------------------------------------------------------------------
// k_init: blocks 0-127 bird rows (x0 = probs@npw+b, u0), 128-255 color rows
// (x0 = npw_row+b, v0). 4 rows/block; k-split slots, 8 accs/thread.
// ---------------------------------------------------------------------------
__global__ __launch_bounds__(256) void k_init(
    const float* __restrict__ probs, const float* __restrict__ npw,
    const float* __restrict__ npb, const float* __restrict__ ew1,
    const float* __restrict__ eb1, float* __restrict__ x0,
    float* __restrict__ u, float* __restrict__ v) {
  __shared__ float As[4][NC];        // 8 KB
  __shared__ float xs[4][HD];        // 2 KB
  __shared__ float part[4][4][HD];   // 8 KB
  const int tid = threadIdx.x, b = blockIdx.x;
  const int cg = tid & 63, slot = tid >> 6;
  const int c0 = 2 * cg;
  float a0, a1, a2, a3, a4, a5, a6, a7;
  if (b < 128) {                     // ---- bird ----
    const int r0 = b * 4;
    const f4* p4 = (const f4*)(probs + r0 * NC);
    ((f4*)As)[tid] = p4[tid]; ((f4*)As)[256 + tid] = p4[256 + tid];
    __syncthreads();
    ZACC(); ACC8(As, npw, 128);      // k=512, 128 per slot
    WRPART();
    __syncthreads();
    for (int i = tid; i < 512; i += 256) {
      int r = i >> 7, cc = i & 127;
      float val = PSUM(r, cc) + npb[cc];
      xs[r][cc] = val;
      x0[(r0 + r) * HD + cc] = val;
    }
    __syncthreads();
    ZACC(); ACC8(xs, ew1, 32);       // u = xs @ ew1_top + eb1
    WRPART();
    __syncthreads();
    for (int i = tid; i < 512; i += 256) {
      int r = i >> 7, cc = i & 127;
      u[(r0 + r) * HD + cc] = PSUM(r, cc) + eb1[cc];
    }
  } else {                           // ---- color ----
    const int cr0 = (b - 128) * 4;
    for (int i = tid; i < 512; i += 256) {
      int r = i >> 7, cc = i & 127;
      float val = npw[(cr0 + r) * HD + cc] + npb[cc];
      xs[r][cc] = val;
      x0[(NB + cr0 + r) * HD + cc] = val;
    }
    __syncthreads();
    ZACC(); ACC8(xs, ew1 + HD * HD, 32);   // v = xs @ ew1_bottom
    WRPART();
    __syncthreads();
    for (int i = tid; i < 512; i += 256) {
      int r = i >> 7, cc = i & 127;
      v[(cr0 + r) * HD + cc] = PSUM(r, cc);
    }
  }
}

// ---------------------------------------------------------------------------
// k_RS: R_i = sum_j relu(u_i+v_j) (blocks 0-127), S_j = sum_i (128-255).
// ---------------------------------------------------------------------------
__global__ __launch_bounds__(256) void k_RS(const float* __restrict__ u,
                                            const float* __restrict__ v,
                                            float* __restrict__ RS) {
  __shared__ float part[8 * HD];
  const int tid = threadIdx.x, b = blockIdx.x;
  const int cg = tid & 31;        // f4 col group
  const int slot = tid >> 5;      // 0..7
  const int row = slot & 3, jh = slot >> 2;
  const float *mine, *other; int r0, ob;
  if (b < 128) { mine = u; other = v; r0 = b * 4;         ob = r0; }
  else         { mine = v; other = u; r0 = (b - 128) * 4; ob = NB + r0; }
  f4 base = *(const f4*)&mine[(r0 + row) * HD + 4 * cg];
  const f4* O4 = (const f4*)other;
  f4 acc = make_float4(0.f, 0.f, 0.f, 0.f);
#pragma unroll 8
  for (int j = jh * 256; j < jh * 256 + 256; ++j) {
    f4 o = O4[j * 32 + cg];
    acc.x += fmaxf(base.x + o.x, 0.f);
    acc.y += fmaxf(base.y + o.y, 0.f);
    acc.z += fmaxf(base.z + o.z, 0.f);
    acc.w += fmaxf(base.w + o.w, 0.f);
  }
  *(f4*)&part[slot * HD + 4 * cg] = acc;
  __syncthreads();
#pragma unroll
  for (int i = 0; i < 2; ++i) {
    int oi = i * 256 + tid;
    int rr = oi >> 7, cc = oi & 127;
    RS[(ob + rr) * HD + cc] = part[rr * HD + cc] + part[(rr + 4) * HD + cc];
  }
}

// ---------------------------------------------------------------------------
// k_layer: aggr = RS@ew2+512*b2; x' = MLP([x,aggr]); u/v(next) = x'@ew1n.
// 256 blocks x 4 node rows; k-split slots, 8 accs/thread, LDS tree-reduce.
// ---------------------------------------------------------------------------
__global__ __launch_bounds__(256) void k_layer(
    const float* __restrict__ xin, const float* __restrict__ RSp,
    const float* __restrict__ ew2l, const float* __restrict__ eb2l,
    const float* __restrict__ nw1l, const float* __restrict__ nb1l,
    const float* __restrict__ nw2l, const float* __restrict__ nb2l,
    const float* __restrict__ ew1n, const float* __restrict__ eb1n,
    float* __restrict__ xout, float* __restrict__ u, float* __restrict__ v) {
  __shared__ float xa[4][HD], rs[4][HD], ag[4][HD], h1[4][HD], xo[4][HD];
  __shared__ float part[4][4][HD];   // 8 KB
  const int tid = threadIdx.x, b = blockIdx.x;
  const int cg = tid & 63, slot = tid >> 6;
  const int c0 = 2 * cg;
  const int nr0 = b * 4;
  const bool bird = b < 128;
  float a0, a1, a2, a3, a4, a5, a6, a7;
  ((f2*)xa)[tid] = ((const f2*)(xin + nr0 * HD))[tid];
  ((f2*)rs)[tid] = ((const f2*)(RSp + nr0 * HD))[tid];
  __syncthreads();

  ZACC(); ACC8(rs, ew2l, 32);                    // phase 1: aggr
  WRPART();
  __syncthreads();
  for (int i = tid; i < 512; i += 256) {
    int r = i >> 7, cc = i & 127;
    ag[r][cc] = PSUM(r, cc) + 512.f * eb2l[cc];
  }
  __syncthreads();

  ZACC();                                        // phase 2: node MLP layer 1
  ACC8(xa, nw1l, 32);
  ACC8(ag, nw1l + HD * HD, 32);
  WRPART();
  __syncthreads();
  for (int i = tid; i < 512; i += 256) {
    int r = i >> 7, cc = i & 127;
    h1[r][cc] = fmaxf(PSUM(r, cc) + nb1l[cc], 0.f);
  }
  __syncthreads();

  ZACC(); ACC8(h1, nw2l, 32);                    // phase 3: node MLP layer 2
  WRPART();
  __syncthreads();
  for (int i = tid; i < 512; i += 256) {
    int r = i >> 7, cc = i & 127;
    float val = PSUM(r, cc) + nb2l[cc];
    xo[r][cc] = val;
    xout[(nr0 + r) * HD + cc] = val;
  }
  if (!ew1n) return;
  __syncthreads();

  ZACC(); ACC8(xo, (bird ? ew1n : ew1n + HD * HD), 32);   // phase 4: next u/v
  WRPART();
  __syncthreads();
  for (int i = tid; i < 512; i += 256) {
    int r = i >> 7, cc = i & 127;
    float val = PSUM(r, cc) + (bird ? eb1n[cc] : 0.f);
    if (bird) u[(nr0 + r) * HD + cc] = val;
    else      v[(nr0 - NB + r) * HD + cc] = val;
  }
}

// ---------------------------------------------------------------------------
// k_final: gnn = x_bird@cpw+b; combined = gnn*probs; out = 1-comb[idx].
// ---------------------------------------------------------------------------
__global__ __launch_bounds__(256) void k_final(
    const float* __restrict__ xf, const float* __restrict__ cpw,
    const float* __restrict__ cpb, const float* __restrict__ probs,
    const int* __restrict__ idx, float* __restrict__ out) {
  __shared__ float xb[4 * HD];
  __shared__ float comb[4 * NC];  // 8 KB
  const int tid = threadIdx.x;
  const int r0 = blockIdx.x * 4;
  ((f2*)xb)[tid] = ((const f2*)(xf + r0 * HD))[tid];
  __syncthreads();
  const f2* W2 = (const f2*)cpw;  // [128][256 f2-cols]
  f2 bb = ((const f2*)cpb)[tid];
  float a00 = bb.x, a01 = bb.y, a10 = bb.x, a11 = bb.y;
  float a20 = bb.x, a21 = bb.y, a30 = bb.x, a31 = bb.y;
#pragma unroll 4
  for (int k = 0; k < HD; ++k) {
    f2 w = W2[k * 256 + tid];
    float x0v = xb[k], x1v = xb[HD + k], x2v = xb[2 * HD + k], x3v = xb[3 * HD + k];
    a00 = fmaf(x0v, w.x, a00); a01 = fmaf(x0v, w.y, a01);
    a10 = fmaf(x1v, w.x, a10); a11 = fmaf(x1v, w.y, a11);
    a20 = fmaf(x2v, w.x, a20); a21 = fmaf(x2v, w.y, a21);
    a30 = fmaf(x3v, w.x, a30); a31 = fmaf(x3v, w.y, a31);
  }
  f2 p0 = ((const f2*)(probs + (r0 + 0) * NC))[tid];
  f2 p1 = ((const f2*)(probs + (r0 + 1) * NC))[tid];
  f2 p2 = ((const f2*)(probs + (r0 + 2) * NC))[tid];
  f2 p3 = ((const f2*)(probs + (r0 + 3) * NC))[tid];
  *(f2*)&comb[0 * NC + 2 * tid] = make_float2(a00 * p0.x, a01 * p0.y);
  *(f2*)&comb[1 * NC + 2 * tid] = make_float2(a10 * p1.x, a11 * p1.y);
  *(f2*)&comb[2 * NC + 2 * tid] = make_float2(a20 * p2.x, a21 * p2.y);
  *(f2*)&comb[3 * NC + 2 * tid] = make_float2(a30 * p3.x, a31 * p3.y);
  __syncthreads();
#pragma unroll
  for (int r = 0; r < 4; ++r)
#pragma unroll
    for (int i = 0; i < 2; ++i) {
      int j = i * 256 + tid;
      int cc = idx[(r0 + r) * NC + j];
      out[(r0 + r) * NC + j] = 1.f - comb[r * NC + cc];
    }
}

extern "C" void kernel_launch(void* const* d_in, const int* in_sizes, int n_in,
                              void* d_out, int out_size, void* d_ws, size_t ws_size,
                              hipStream_t stream) {
  const float* probs = (const float*)d_in[0];
  const float* npw   = (const float*)d_in[1];
  const float* npb   = (const float*)d_in[2];
  const float* ew1   = (const float*)d_in[3];
  const float* eb1   = (const float*)d_in[4];
  const float* ew2   = (const float*)d_in[5];
  const float* eb2   = (const float*)d_in[6];
  const float* nw1   = (const float*)d_in[7];
  const float* nb1   = (const float*)d_in[8];
  const float* nw2   = (const float*)d_in[9];
  const float* nb2   = (const float*)d_in[10];
  const float* cpw   = (const float*)d_in[11];
  const float* cpb   = (const float*)d_in[12];
  float* out = (float*)d_out;

  float* x0 = (float*)d_ws;          // 1024*128
  float* x1 = x0 + 1024 * HD;
  float* ua = x1 + 1024 * HD;        // 512*128 each
  float* va = ua + NB * HD;
  float* ub = va + NC * HD;
  float* vb = ub + NB * HD;
  float* RS = vb + NC * HD;          // 1024*128
  int*  idx = (int*)(RS + 1024 * HD);

  k_sort <<<512, 512, 0, stream>>>(probs, idx);
  k_init <<<256, 256, 0, stream>>>(probs, npw, npb, ew1, eb1, x0, ua, va);

  // layer 0: x0 -> x1, (ua,va) -> (ub,vb)
  k_RS   <<<256, 256, 0, stream>>>(ua, va, RS);
  k_layer<<<256, 256, 0, stream>>>(x0, RS, ew2, eb2, nw1, nb1, nw2, nb2,
                                   ew1 + 32768, eb1 + HD, x1, ub, vb);
  // layer 1: x1 -> x0, (ub,vb) -> (ua,va)
  k_RS   <<<256, 256, 0, stream>>>(ub, vb, RS);
  k_layer<<<256, 256, 0, stream>>>(x1, RS, ew2 + 16384, eb2 + HD,
                                   nw1 + 32768, nb1 + HD, nw2 + 16384, nb2 + HD,
                                   ew1 + 65536, eb1 + 2 * HD, x0, ua, va);
  // layer 2: x0 -> x1, no next u/v
  k_RS   <<<256, 256, 0, stream>>>(ua, va, RS);
  k_layer<<<256, 256, 0, stream>>>(x0, RS, ew2 + 32768, eb2 + 2 * HD,
                                   nw1 + 65536, nb1 + 2 * HD, nw2 + 32768, nb2 + 2 * HD,
                                   nullptr, nullptr, x1, nullptr, nullptr);
  // epilogue: gnn + combine + gather
  k_final<<<128, 256, 0, stream>>>(x1, cpw, cpb, probs, idx, out);
}

// Round 7
// 89.618 us; speedup vs baseline: 4.3551x; 1.5346x over previous
//
#include <hip/hip_runtime.h>

#define NB 512
#define NC 512
#define HD 128
typedef float2 f2;
typedef float4 f4;

// 8-slot k-split matmul: thread = (cg: f2 output col, slot: k-eighth).
// Each weight load feeds 8 FMAs (4 rows x 2 cols); loads independent.
#define ACC8(SRC, WP, KQ) { const f2* W2_ = (const f2*)(WP); \
  _Pragma("unroll 8") for (int kk_ = 0; kk_ < (KQ); ++kk_) { \
    int k_ = slot * (KQ) + kk_; \
    f2 w_ = W2_[k_ * 64 + cg]; \
    float s0_ = SRC[0][k_], s1_ = SRC[1][k_], s2_ = SRC[2][k_], s3_ = SRC[3][k_]; \
    a0 = fmaf(s0_, w_.x, a0); a1 = fmaf(s0_, w_.y, a1); \
    a2 = fmaf(s1_, w_.x, a2); a3 = fmaf(s1_, w_.y, a3); \
    a4 = fmaf(s2_, w_.x, a4); a5 = fmaf(s2_, w_.y, a5); \
    a6 = fmaf(s3_, w_.x, a6); a7 = fmaf(s3_, w_.y, a7); } }
#define ZACC() { a0=a1=a2=a3=a4=a5=a6=a7=0.f; }
#define WRPART() { *(f2*)&part[slot][0][c0] = make_float2(a0, a1); \
  *(f2*)&part[slot][1][c0] = make_float2(a2, a3); \
  *(f2*)&part[slot][2][c0] = make_float2(a4, a5); \
  *(f2*)&part[slot][3][c0] = make_float2(a6, a7); }
#define PSUM(r_, cc_) (part[0][r_][cc_] + part[1][r_][cc_] + part[2][r_][cc_] + \
                       part[3][r_][cc_] + part[4][r_][cc_] + part[5][r_][cc_] + \
                       part[6][r_][cc_] + part[7][r_][cc_])

// ---------------------------------------------------------------------------
// k_pre: 256 blocks x 512 thr.
//  - sort rows 2b, 2b+1 (stable-descending rank, lax.top_k semantics)
//  - blocks 0-127: bird rows 4b..4b+3: x0 = probs@npw+b, u0 = x0@ew1_top+eb1
//  - blocks 128-255: color rows: x0 = npw_row+b, v0 = x0@ew1_bot
// ---------------------------------------------------------------------------
__global__ __launch_bounds__(512) void k_pre(
    const float* __restrict__ probs, const float* __restrict__ npw,
    const float* __restrict__ npb, const float* __restrict__ ew1,
    const float* __restrict__ eb1, float* __restrict__ x0,
    float* __restrict__ u, float* __restrict__ v, int* __restrict__ idx) {
  __shared__ float srt[2][NC];       // 4 KB
  __shared__ float As[4][NC];        // 8 KB
  __shared__ float xs[4][HD];        // 2 KB
  __shared__ float part[8][4][HD];   // 16 KB
  const int tid = threadIdx.x, b = blockIdx.x;
  const int cg = tid & 63, slot = tid >> 6;
  const int c0 = 2 * cg;
  float a0, a1, a2, a3, a4, a5, a6, a7;

  // ---- sort: rows 2b, 2b+1, one half-block per row, 2 elements/thread ----
  {
    const int h = tid >> 8, e = tid & 255;
    const int srow = 2 * b + h;
    srt[h][e]       = probs[srow * NC + e];
    srt[h][e + 256] = probs[srow * NC + e + 256];
    __syncthreads();
    const float v0 = srt[h][e], v1 = srt[h][e + 256];
    int r0_ = 0, r1_ = 0;
#pragma unroll 8
    for (int j4 = 0; j4 < 128; ++j4) {
      f4 sv = ((const f4*)&srt[h][0])[j4];
      int j = 4 * j4;
      r0_ += (sv.x > v0) || (sv.x == v0 && (j + 0) < e);
      r0_ += (sv.y > v0) || (sv.y == v0 && (j + 1) < e);
      r0_ += (sv.z > v0) || (sv.z == v0 && (j + 2) < e);
      r0_ += (sv.w > v0) || (sv.w == v0 && (j + 3) < e);
      r1_ += (sv.x > v1) || (sv.x == v1 && (j + 0) < e + 256);
      r1_ += (sv.y > v1) || (sv.y == v1 && (j + 1) < e + 256);
      r1_ += (sv.z > v1) || (sv.z == v1 && (j + 2) < e + 256);
      r1_ += (sv.w > v1) || (sv.w == v1 && (j + 3) < e + 256);
    }
    idx[srow * NC + r0_] = e;
    idx[srow * NC + r1_] = e + 256;
  }

  if (b < 128) {                     // ---- bird ----
    const int r0 = b * 4;
    ((f4*)As)[tid] = ((const f4*)(probs + r0 * NC))[tid];
    __syncthreads();
    ZACC(); ACC8(As, npw, 64);       // k=512, 64 per slot
    WRPART();
    __syncthreads();
    { int r = tid >> 7, cc = tid & 127;
      float val = PSUM(r, cc) + npb[cc];
      xs[r][cc] = val;
      x0[(r0 + r) * HD + cc] = val; }
    __syncthreads();
    ZACC(); ACC8(xs, ew1, 16);       // u = xs @ ew1_top + eb1
    WRPART();
    __syncthreads();
    { int r = tid >> 7, cc = tid & 127;
      u[(r0 + r) * HD + cc] = PSUM(r, cc) + eb1[cc]; }
  } else {                           // ---- color ----
    const int cr0 = (b - 128) * 4;
    { int r = tid >> 7, cc = tid & 127;
      float val = npw[(cr0 + r) * HD + cc] + npb[cc];
      xs[r][cc] = val;
      x0[(NB + cr0 + r) * HD + cc] = val; }
    __syncthreads();
    ZACC(); ACC8(xs, ew1 + HD * HD, 16);   // v = xs @ ew1_bottom
    WRPART();
    __syncthreads();
    { int r = tid >> 7, cc = tid & 127;
      v[(cr0 + r) * HD + cc] = PSUM(r, cc); }
  }
}

// ---------------------------------------------------------------------------
// k_RSlayer: fused relu-sum + layer. Block b owns node rows 4b..4b+3
// (bird for b<128, color for b>=128). RS never leaves LDS.
// ---------------------------------------------------------------------------
__global__ __launch_bounds__(512) void k_RSlayer(
    const float* __restrict__ xin, const float* __restrict__ uin,
    const float* __restrict__ vin,
    const float* __restrict__ ew2l, const float* __restrict__ eb2l,
    const float* __restrict__ nw1l, const float* __restrict__ nb1l,
    const float* __restrict__ nw2l, const float* __restrict__ nb2l,
    const float* __restrict__ ew1n, const float* __restrict__ eb1n,
    float* __restrict__ xout, float* __restrict__ uout, float* __restrict__ vout) {
  __shared__ float rsp[16][HD];      // 8 KB RS partials
  __shared__ float xa[4][HD], rs[4][HD], ag[4][HD], h1[4][HD], xo[4][HD];
  __shared__ float part[8][4][HD];   // 16 KB
  const int tid = threadIdx.x, b = blockIdx.x;
  const int cg = tid & 63, slot = tid >> 6;
  const int c0 = 2 * cg;
  const int nr0 = b * 4;
  const bool bird = b < 128;
  const int r0s = (b & 127) * 4;
  float a0, a1, a2, a3, a4, a5, a6, a7;

  if (tid < 256) ((f2*)xa)[tid] = ((const f2*)(xin + nr0 * HD))[tid];

  // ---- RS phase: 16 slots = 4 rows x 4 j-quarters, f4 loads from L2 ----
  {
    const float* mine  = bird ? uin : vin;
    const float* other = bird ? vin : uin;
    const int s16 = tid >> 5, cg32 = tid & 31;
    const int row = s16 & 3, jq = s16 >> 2;
    f4 base = *(const f4*)&mine[(r0s + row) * HD + 4 * cg32];
    const f4* O4 = (const f4*)other;
    f4 acc = make_float4(0.f, 0.f, 0.f, 0.f);
#pragma unroll 8
    for (int j = jq * 128; j < jq * 128 + 128; ++j) {
      f4 o = O4[j * 32 + cg32];
      acc.x += fmaxf(base.x + o.x, 0.f);
      acc.y += fmaxf(base.y + o.y, 0.f);
      acc.z += fmaxf(base.z + o.z, 0.f);
      acc.w += fmaxf(base.w + o.w, 0.f);
    }
    *(f4*)&rsp[s16][4 * cg32] = acc;
  }
  __syncthreads();
  { int r = tid >> 7, cc = tid & 127;
    rs[r][cc] = rsp[r][cc] + rsp[4 + r][cc] + rsp[8 + r][cc] + rsp[12 + r][cc]; }
  __syncthreads();

  ZACC(); ACC8(rs, ew2l, 16);                    // phase 1: aggr
  WRPART();
  __syncthreads();
  { int r = tid >> 7, cc = tid & 127;
    ag[r][cc] = PSUM(r, cc) + 512.f * eb2l[cc]; }
  __syncthreads();

  ZACC();                                        // phase 2: node MLP layer 1
  ACC8(xa, nw1l, 16);
  ACC8(ag, nw1l + HD * HD, 16);
  WRPART();
  __syncthreads();
  { int r = tid >> 7, cc = tid & 127;
    h1[r][cc] = fmaxf(PSUM(r, cc) + nb1l[cc], 0.f); }
  __syncthreads();

  ZACC(); ACC8(h1, nw2l, 16);                    // phase 3: node MLP layer 2
  WRPART();
  __syncthreads();
  { int r = tid >> 7, cc = tid & 127;
    float val = PSUM(r, cc) + nb2l[cc];
    xo[r][cc] = val;
    xout[(nr0 + r) * HD + cc] = val; }
  __syncthreads();

  ZACC(); ACC8(xo, (bird ? ew1n : ew1n + HD * HD), 16);   // phase 4: next u/v
  WRPART();
  __syncthreads();
  { int r = tid >> 7, cc = tid & 127;
    float val = PSUM(r, cc) + (bird ? eb1n[cc] : 0.f);
    if (bird) uout[(nr0 + r) * HD + cc] = val;
    else      vout[(nr0 - NB + r) * HD + cc] = val; }
}

// ---------------------------------------------------------------------------
// k_last: 128 blocks x 4 bird rows. R-sum + aggr + node MLP + gnn scores +
// combine with probs + idx-gather -> d_out. (S and color x' are dead.)
// ---------------------------------------------------------------------------
__global__ __launch_bounds__(512) void k_last(
    const float* __restrict__ xin, const float* __restrict__ uin,
    const float* __restrict__ vin,
    const float* __restrict__ ew2l, const float* __restrict__ eb2l,
    const float* __restrict__ nw1l, const float* __restrict__ nb1l,
    const float* __restrict__ nw2l, const float* __restrict__ nb2l,
    const float* __restrict__ cpw, const float* __restrict__ cpb,
    const float* __restrict__ probs, const int* __restrict__ idx,
    float* __restrict__ out) {
  __shared__ float rsp[16][HD];      // 8 KB
  __shared__ float xa[4][HD], rs[4][HD], ag[4][HD], h1[4][HD], xo[4][HD];
  __shared__ float part[8][4][HD];   // 16 KB
  __shared__ float comb[4][NC];      // 8 KB
  const int tid = threadIdx.x, b = blockIdx.x;
  const int cg = tid & 63, slot = tid >> 6;
  const int c0 = 2 * cg;
  const int nr0 = b * 4;
  float a0, a1, a2, a3, a4, a5, a6, a7;

  if (tid < 256) ((f2*)xa)[tid] = ((const f2*)(xin + nr0 * HD))[tid];

  {  // ---- R phase over v ----
    const int s16 = tid >> 5, cg32 = tid & 31;
    const int row = s16 & 3, jq = s16 >> 2;
    f4 base = *(const f4*)&uin[(nr0 + row) * HD + 4 * cg32];
    const f4* O4 = (const f4*)vin;
    f4 acc = make_float4(0.f, 0.f, 0.f, 0.f);
#pragma unroll 8
    for (int j = jq * 128; j < jq * 128 + 128; ++j) {
      f4 o = O4[j * 32 + cg32];
      acc.x += fmaxf(base.x + o.x, 0.f);
      acc.y += fmaxf(base.y + o.y, 0.f);
      acc.z += fmaxf(base.z + o.z, 0.f);
      acc.w += fmaxf(base.w + o.w, 0.f);
    }
    *(f4*)&rsp[s16][4 * cg32] = acc;
  }
  __syncthreads();
  { int r = tid >> 7, cc = tid & 127;
    rs[r][cc] = rsp[r][cc] + rsp[4 + r][cc] + rsp[8 + r][cc] + rsp[12 + r][cc]; }
  __syncthreads();

  ZACC(); ACC8(rs, ew2l, 16);
  WRPART();
  __syncthreads();
  { int r = tid >> 7, cc = tid & 127;
    ag[r][cc] = PSUM(r, cc) + 512.f * eb2l[cc]; }
  __syncthreads();

  ZACC();
  ACC8(xa, nw1l, 16);
  ACC8(ag, nw1l + HD * HD, 16);
  WRPART();
  __syncthreads();
  { int r = tid >> 7, cc = tid & 127;
    h1[r][cc] = fmaxf(PSUM(r, cc) + nb1l[cc], 0.f); }
  __syncthreads();

  ZACC(); ACC8(h1, nw2l, 16);
  WRPART();
  __syncthreads();
  { int r = tid >> 7, cc = tid & 127;
    xo[r][cc] = PSUM(r, cc) + nb2l[cc]; }
  __syncthreads();

  // ---- gnn scores + combine: thread = one output column, 4 rows ----
  {
    const int c = tid;
    float s0 = cpb[c], s1 = s0, s2 = s0, s3 = s0;
#pragma unroll 8
    for (int k = 0; k < HD; ++k) {
      float w = cpw[k * NC + c];
      s0 = fmaf(xo[0][k], w, s0);
      s1 = fmaf(xo[1][k], w, s1);
      s2 = fmaf(xo[2][k], w, s2);
      s3 = fmaf(xo[3][k], w, s3);
    }
    comb[0][c] = s0 * probs[(nr0 + 0) * NC + c];
    comb[1][c] = s1 * probs[(nr0 + 1) * NC + c];
    comb[2][c] = s2 * probs[(nr0 + 2) * NC + c];
    comb[3][c] = s3 * probs[(nr0 + 3) * NC + c];
  }
  __syncthreads();
#pragma unroll
  for (int i = 0; i < 4; ++i) {
    int ii = i * 512 + tid;
    int r = ii >> 9, j = ii & 511;
    int cc = idx[(nr0 + r) * NC + j];
    out[(nr0 + r) * NC + j] = 1.f - comb[r][cc];
  }
}

extern "C" void kernel_launch(void* const* d_in, const int* in_sizes, int n_in,
                              void* d_out, int out_size, void* d_ws, size_t ws_size,
                              hipStream_t stream) {
  const float* probs = (const float*)d_in[0];
  const float* npw   = (const float*)d_in[1];
  const float* npb   = (const float*)d_in[2];
  const float* ew1   = (const float*)d_in[3];
  const float* eb1   = (const float*)d_in[4];
  const float* ew2   = (const float*)d_in[5];
  const float* eb2   = (const float*)d_in[6];
  const float* nw1   = (const float*)d_in[7];
  const float* nb1   = (const float*)d_in[8];
  const float* nw2   = (const float*)d_in[9];
  const float* nb2   = (const float*)d_in[10];
  const float* cpw   = (const float*)d_in[11];
  const float* cpb   = (const float*)d_in[12];
  float* out = (float*)d_out;

  float* x0 = (float*)d_ws;          // 1024*128
  float* x1 = x0 + 1024 * HD;
  float* ua = x1 + 1024 * HD;        // 512*128 each
  float* va = ua + NB * HD;
  float* ub = va + NC * HD;
  float* vb = ub + NB * HD;
  int*  idx = (int*)(vb + NC * HD);  // 512*512

  k_pre    <<<256, 512, 0, stream>>>(probs, npw, npb, ew1, eb1, x0, ua, va, idx);
  // layer 0: x0 -> x1, (ua,va) -> (ub,vb)
  k_RSlayer<<<256, 512, 0, stream>>>(x0, ua, va, ew2, eb2, nw1, nb1, nw2, nb2,
                                     ew1 + 32768, eb1 + HD, x1, ub, vb);
  // layer 1: x1 -> x0, (ub,vb) -> (ua,va)
  k_RSlayer<<<256, 512, 0, stream>>>(x1, ub, vb, ew2 + 16384, eb2 + HD,
                                     nw1 + 32768, nb1 + HD, nw2 + 16384, nb2 + HD,
                                     ew1 + 65536, eb1 + 2 * HD, x0, ua, va);
  // layer 2 (bird only) fused through to d_out
  k_last   <<<128, 512, 0, stream>>>(x0, ua, va, ew2 + 32768, eb2 + 2 * HD,
                                     nw1 + 65536, nb1 + 2 * HD,
                                     nw2 + 32768, nb2 + 2 * HD,
                                     cpw, cpb, probs, idx, out);
}